// Round 10
// baseline (215.595 us; speedup 1.0000x reference)
//
#include <hip/hip_runtime.h>

// FWEnergyGAD: element-wise double-well energy + forces + GAD direction +
// 2x2 Hessian eigendecomposition (closed form).
//
// Outputs concatenated flat in return order (n = B):
//   [0,     n)   energy
//   [n,    3n)   forces      (B,2)
//   [3n,   5n)   energy_grad (B,2)
//   [5n,   9n)   hessian     (B,2,2)
//   [9n,  10n)   eigenval 0  (smaller)
//   [10n, 11n)   eigenval 1  (larger)
//
// v9: FILL-SHAPED CONCURRENCY. Eight full-occupancy variants (v1-v8:
// ILP, burst, NT, native math, persistence, output-major, phase-separated
// R/W) all land at 88-104us (~3.4 B/cyc/CU write rate). The harness fill
// hits 6.7 TB/s (10.9 B/cyc/CU) at ~3 waves/CU -- 12x FEWER resident
// waves than every variant I ran. Theory: 2048 resident blocks x 6 output
// streams ~= 12K interleaved write streams chip-wide; HBM controllers'
// reorder windows can't find row-buffer locality. The fill presents ~1.5K
// slowly-advancing sequential streams. v9 mimics it: 256 blocks (1/CU,
// 4 waves/CU), each owning a CONTIGUOUS 16384-point chunk, marching
// sequentially -> 1536 strictly-sequential write streams. Depth-2 input
// prefetch hides read latency at low occupancy; 2 pts/thread/iter makes
// all stores vector (f2/f4) and loads 16B.

typedef float f2v __attribute__((ext_vector_type(2)));
typedef float f4v __attribute__((ext_vector_type(4)));

#define BLOCK 256
#define GRID 256

namespace {

struct PointOut {
    float e, fx, fy, gx, gy, hxx, hyy, l0, l1;
};

__device__ __forceinline__ PointOut compute_point(float px, float py) {
    const float BETA = 0.1f;
    PointOut o;
    float u = px - 0.5f;
    float v = py - 0.5f;
    float uu = u * u;
    float vv = v * v;
    float a = uu - 1.0f;   // u^2 - 1
    float b = vv - 1.0f;   // v^2 - 1

    o.e = a * a + b * b + BETA * u * v;

    float gx = 4.0f * u * a + BETA * v;
    float gy = 4.0f * v * b + BETA * u;
    o.fx = -gx;
    o.fy = -gy;

    o.hxx = 12.0f * uu - 4.0f;
    o.hyy = 12.0f * vv - 4.0f;
    // hxy = BETA (constant)

    // 2x2 symmetric eigendecomposition, closed form.
    float d = 0.5f * (o.hxx - o.hyy);
    float m = 0.5f * (o.hxx + o.hyy);
    float r = __builtin_amdgcn_sqrtf(d * d + BETA * BETA);  // r >= 0.1
    o.l0 = m - r;                        // smaller eigenvalue
    o.l1 = m + r;                        // larger eigenvalue

    // Eigenvector of l0; select-branch avoids fp32 cancellation (|d| up
    // to ~380 vs hxy=0.1; wrong branch computes r-|d|).
    bool pos = (d >= 0.0f);
    float wx = pos ? BETA : (d - r);
    float wy = pos ? -(d + r) : BETA;
    float n2 = wx * wx + wy * wy;        // >= 0.01

    // gad = -f + 2 (f.w_hat) w_hat ; sign of w irrelevant (quadratic).
    float fd = o.fx * wx + o.fy * wy;
    float s = (2.0f * fd) * __builtin_amdgcn_rcpf(n2);
    float gadx = -o.fx + s * wx;
    float gady = -o.fy + s * wy;

    float prod = o.l0 * o.l1;            // reference's eigval product
    float g2 = gadx * gadx + gady * gady;   // gmag^2; gmag<1 <=> g2<1
    if (prod > 0.0f && g2 < 1.0f) {
        float inv = __builtin_amdgcn_rsqf(fmaxf(g2, 1e-60f));
        gadx *= inv;
        gady *= inv;
    }
    // TAU = 1.0 -> energy_grad == gad
    o.gx = gadx;
    o.gy = gady;
    return o;
}

}  // namespace

// Fast path: n % 4 == 0 (all stream bases f4-aligned). Each block owns a
// contiguous chunk of point-PAIRS and marches through it sequentially.
__global__ __launch_bounds__(BLOCK) void fw_chunk_kernel(
    const f4v* __restrict__ in4, float* __restrict__ out, int n) {
    const float BETA = 0.1f;
    int t = threadIdx.x;
    int np = n >> 1;                                  // point pairs
    int ppb = (np + GRID - 1) / GRID;                 // pairs per block
    int start = blockIdx.x * ppb;
    int end   = min(start + ppb, np);

    size_t N = (size_t)n;
    f2v* e_out  = (f2v*)out;                          // pair j -> f2 at j
    f4v* f_out  = (f4v*)(out + N);                    // pair j -> f4 at j
    f4v* g_out  = (f4v*)(out + 3 * N);                // pair j -> f4 at j
    f4v* h_out  = (f4v*)(out + 5 * N);                // pair j -> f4 at 2j,2j+1
    f2v* l0_out = (f2v*)(out + 9 * N);                // pair j -> f2 at j
    f2v* l1_out = (f2v*)(out + 10 * N);               // pair j -> f2 at j

    // Depth-2 prefetch pipeline: load pair j+2*BLOCK while computing j.
    int j0 = start + t;
    f4v p0, p1;
    if (j0 < end)         p0 = in4[j0];
    if (j0 + BLOCK < end) p1 = in4[j0 + BLOCK];

    for (int j = j0; j < end; j += BLOCK) {
        int jn = j + 2 * BLOCK;
        f4v nxt = p0;                                 // dummy init
        if (jn < end) nxt = in4[jn];

        f4v cur = p0;
        p0 = p1;
        p1 = nxt;

        PointOut o0 = compute_point(cur.x, cur.y);
        PointOut o1 = compute_point(cur.z, cur.w);

        f2v e; e.x = o0.e; e.y = o1.e;
        e_out[j] = e;
        f4v f; f.x = o0.fx; f.y = o0.fy; f.z = o1.fx; f.w = o1.fy;
        f_out[j] = f;
        f4v g; g.x = o0.gx; g.y = o0.gy; g.z = o1.gx; g.w = o1.gy;
        g_out[j] = g;
        f4v h0; h0.x = o0.hxx; h0.y = BETA; h0.z = BETA; h0.w = o0.hyy;
        f4v h1; h1.x = o1.hxx; h1.y = BETA; h1.z = BETA; h1.w = o1.hyy;
        h_out[2 * (size_t)j]     = h0;
        h_out[2 * (size_t)j + 1] = h1;
        f2v l0; l0.x = o0.l0; l0.y = o1.l0;
        l0_out[j] = l0;
        f2v l1; l1.x = o0.l1; l1.y = o1.l1;
        l1_out[j] = l1;
    }
}

// Fallback (n % 4 != 0): point-major scalar kernel, known-correct (v4).
__global__ __launch_bounds__(BLOCK) void fw_energy_gad_scalar(
    const f2v* __restrict__ in, float* __restrict__ out, int n) {
    int i = blockIdx.x * blockDim.x + threadIdx.x;
    if (i >= n) return;
    const float BETA = 0.1f;
    f2v pt = in[i];
    PointOut o = compute_point(pt.x, pt.y);
    size_t N = (size_t)n;
    out[i] = o.e;
    f2v fo; fo.x = o.fx; fo.y = o.fy;
    ((f2v*)(out + N))[i] = fo;
    f2v go; go.x = o.gx; go.y = o.gy;
    ((f2v*)(out + 3 * N))[i] = go;
    out[5 * N + 4 * (size_t)i]     = o.hxx;
    out[5 * N + 4 * (size_t)i + 1] = BETA;
    out[5 * N + 4 * (size_t)i + 2] = BETA;
    out[5 * N + 4 * (size_t)i + 3] = o.hyy;
    out[9 * N + i]  = o.l0;
    out[10 * N + i] = o.l1;
}

extern "C" void kernel_launch(void* const* d_in, const int* in_sizes, int n_in,
                              void* d_out, int out_size, void* d_ws, size_t ws_size,
                              hipStream_t stream) {
    const float* in = (const float*)d_in[0];
    float* out = (float*)d_out;
    int n = in_sizes[0] / 2;   // B points, each (x, y)

    if ((n & 3) == 0) {
        fw_chunk_kernel<<<GRID, BLOCK, 0, stream>>>((const f4v*)in, out, n);
    } else {
        int grid = (n + BLOCK - 1) / BLOCK;
        fw_energy_gad_scalar<<<grid, BLOCK, 0, stream>>>((const f2v*)in, out, n);
    }
}